// Round 3
// baseline (716.378 us; speedup 1.0000x reference)
//
#include <hip/hip_runtime.h>
#include <hip/hip_bf16.h>

typedef unsigned short u16;
typedef unsigned int   u32;

typedef __attribute__((ext_vector_type(8))) short bf16x8;  // 8 bf16 = 4 VGPRs
typedef __attribute__((ext_vector_type(4))) float f32x4;   // MFMA 16x16 accum

constexpr int N_AUDIO = 480000;
constexpr int K_IR    = 240000;

// k' (shifted tap index) range needed: [0, K + 15 + 768) = [0, 240783)
constexpr int NSPLIT  = 40;
constexpr int LSPLIT  = 6048;             // mult of 32; 40*6048 = 241920 >= 240783
constexpr int ITERS   = LSPLIT / 32;      // 189 k-steps per split
constexpr int NGROUP  = 118;              // ceil(480000 / 4096) output groups

// padded bf16 audio: max read = 479232+240+24+235872+3072+6016+8 = 724464
constexpr int A_ELEMS = 724992;
// IR phase rows: row p holds ir_p[x] = ir[x-p], x in [-IR_PAD, ROW_IR-IR_PAD)
constexpr int IR_PAD  = 784;              // covers -8 - 256*3 = -776 front underrun
constexpr int ROW_IR  = 242752;           // >= 784 + 241920 + 32, mult of 16
constexpr int IR_ELEMS = 8 * ROW_IR;      // 1,942,016

// ws layout (bytes), all 16B aligned
constexpr size_t OFF_A   = 0;
constexpr size_t OFF_IR  = (size_t)A_ELEMS * 2;              // 1,449,984
constexpr size_t OFF_ACC = OFF_IR + (size_t)IR_ELEMS * 2;    // 5,334,016
constexpr size_t OFF_MAX = OFF_ACC + (size_t)N_AUDIO * 4;    // 7,254,016

__device__ __forceinline__ u16 f2bf(float f) {
    u32 u = __float_as_uint(f);
    u32 r = (u + 0x7fffu + ((u >> 16) & 1u)) >> 16;   // RTN
    return (u16)r;
}

// ---- kernel 1: convert inputs to bf16 (audio padded, IR in 8 phase rows), zero accum+slot
__global__ void prep_kernel(const float* __restrict__ audio, const float* __restrict__ ir,
                            u16* __restrict__ abuf, u16* __restrict__ irbuf,
                            float* __restrict__ accum, u32* __restrict__ slot) {
    int tid = blockIdx.x * blockDim.x + threadIdx.x;
    int nth = gridDim.x * blockDim.x;
    if (tid == 0) *slot = 0u;
    for (int i = tid; i < A_ELEMS; i += nth)
        abuf[i] = (i < N_AUDIO) ? f2bf(audio[i]) : (u16)0;
    for (int i = tid; i < IR_ELEMS; i += nth) {
        int p = i / ROW_IR;               // phase 0..7
        int x = (i - p * ROW_IR) - IR_PAD;
        int src = x - p;
        irbuf[i] = (src >= 0 && src < K_IR) ? f2bf(ir[src]) : (u16)0;
    }
    for (int i = tid; i < N_AUDIO; i += nth) accum[i] = 0.0f;
}

// ---- kernel 2: MFMA correlation, MT=4 x NT=4 tiles/wave (4096 outs), split-K via atomicAdd
// C[m][n] = out[gbase + 1024*mt + 256*nt + 16m + n]
// A[m][k'] = audio[gbase + 1024*mt + 16m + k'] (16B-aligned per-lane loads)
// B[k'][n] = ir[k' - n - 256*nt] read from phase row (n&7) at aligned offset.
__global__ __launch_bounds__(256) void conv_kernel(const u16* __restrict__ abuf,
                                                   const u16* __restrict__ irbuf,
                                                   float* __restrict__ accum) {
    const int wave = threadIdx.x >> 6;
    const int lane = threadIdx.x & 63;
    const int gid  = blockIdx.x * 4 + wave;          // 0..4719
    const int s    = gid / NGROUP;                   // k-split 0..39
    const int g    = gid - s * NGROUP;               // output group 0..117

    const int m16 = lane & 15;                       // A row m / B col n / C col
    const int kq  = lane >> 4;                       // 0..3 (k-chunk quadrant)
    const int nh  = m16 >> 3;                        // n high bit
    const int ph  = m16 & 7;                         // IR phase row

    const int gbase = g * 4096;
    const int k0    = s * LSPLIT;

    const u16* aptr = abuf + gbase + 16 * m16 + 8 * kq + k0;
    const u16* bptr = irbuf + ph * ROW_IR + IR_PAD + k0 + 8 * (kq - nh);

    f32x4 acc[4][4];
    #pragma unroll
    for (int mt = 0; mt < 4; ++mt)
        #pragma unroll
        for (int nt = 0; nt < 4; ++nt)
            acc[mt][nt] = (f32x4){0.f, 0.f, 0.f, 0.f};

    #pragma unroll 2
    for (int it = 0; it < ITERS; ++it) {
        bf16x8 b[4], a[4];
        #pragma unroll
        for (int nt = 0; nt < 4; ++nt)
            b[nt] = *(const bf16x8*)(bptr - 256 * nt);
        #pragma unroll
        for (int mt = 0; mt < 4; ++mt)
            a[mt] = *(const bf16x8*)(aptr + 1024 * mt);
        #pragma unroll
        for (int mt = 0; mt < 4; ++mt)
            #pragma unroll
            for (int nt = 0; nt < 4; ++nt)
                acc[mt][nt] = __builtin_amdgcn_mfma_f32_16x16x32_bf16(a[mt], b[nt], acc[mt][nt], 0, 0, 0);
        aptr += 32;
        bptr += 32;
    }

    // C/D layout: col = lane&15, row = (lane>>4)*4 + r  ->  t = base + 16*row + col
    #pragma unroll
    for (int mt = 0; mt < 4; ++mt) {
        #pragma unroll
        for (int nt = 0; nt < 4; ++nt) {
            int base = gbase + 1024 * mt + 256 * nt + 64 * kq + m16;
            #pragma unroll
            for (int r = 0; r < 4; ++r) {
                int t = base + 16 * r;
                if (t < N_AUDIO) atomicAdd(&accum[t], acc[mt][nt][r]);
            }
        }
    }
}

// ---- kernel 3: global abs-max (float-bits atomicMax works for non-negative floats)
__global__ __launch_bounds__(256) void reduce_max_kernel(const float* __restrict__ accum,
                                                         u32* __restrict__ slot) {
    int tid = blockIdx.x * blockDim.x + threadIdx.x;
    int nth = gridDim.x * blockDim.x;
    float m = 0.f;
    for (int i = tid; i < N_AUDIO; i += nth) m = fmaxf(m, fabsf(accum[i]));
    for (int off = 32; off > 0; off >>= 1) m = fmaxf(m, __shfl_down(m, off, 64));
    __shared__ float smax[4];
    if ((threadIdx.x & 63) == 0) smax[threadIdx.x >> 6] = m;
    __syncthreads();
    if (threadIdx.x == 0) {
        float b = fmaxf(fmaxf(smax[0], smax[1]), fmaxf(smax[2], smax[3]));
        atomicMax(slot, __float_as_uint(b));
    }
}

// ---- kernel 4: normalize
__global__ __launch_bounds__(256) void scale_kernel(const float* __restrict__ accum,
                                                    const u32* __restrict__ slot,
                                                    float* __restrict__ out) {
    float inv = 1.0f / __uint_as_float(*slot);
    int t = blockIdx.x * 256 + threadIdx.x;
    if (t < N_AUDIO) out[t] = accum[t] * inv;
}

extern "C" void kernel_launch(void* const* d_in, const int* in_sizes, int n_in,
                              void* d_out, int out_size, void* d_ws, size_t ws_size,
                              hipStream_t stream) {
    const float* audio = (const float*)d_in[0];
    const float* ir    = (const float*)d_in[1];
    float* out = (float*)d_out;

    char* ws = (char*)d_ws;
    u16*   abuf  = (u16*)(ws + OFF_A);
    u16*   irbuf = (u16*)(ws + OFF_IR);
    float* accum = (float*)(ws + OFF_ACC);
    u32*   slot  = (u32*)(ws + OFF_MAX);

    prep_kernel<<<2048, 256, 0, stream>>>(audio, ir, abuf, irbuf, accum, slot);
    conv_kernel<<<NGROUP * NSPLIT / 4, 256, 0, stream>>>(abuf, irbuf, accum);
    reduce_max_kernel<<<960, 256, 0, stream>>>(accum, slot);
    scale_kernel<<<(N_AUDIO + 255) / 256, 256, 0, stream>>>(accum, slot, out);
}

// Round 4
// 645.793 us; speedup vs baseline: 1.1093x; 1.1093x over previous
//
#include <hip/hip_runtime.h>
#include <hip/hip_bf16.h>

typedef unsigned short u16;
typedef unsigned int   u32;

typedef __attribute__((ext_vector_type(8))) short bf16x8;  // 8 bf16 = 4 VGPRs
typedef __attribute__((ext_vector_type(4))) float f32x4;   // MFMA 16x16 accum

constexpr int N_AUDIO = 480000;
constexpr int K_IR    = 240000;

// k' (shifted tap index) range needed: [0, K + 15 + 768) = [0, 240783)
constexpr int NSPLIT  = 40;
constexpr int LSPLIT  = 6048;             // mult of 32; 40*6048 = 241920 >= 240783
constexpr int ITERS   = LSPLIT / 32;      // 189 k-steps per split (odd, see pipeline)
constexpr int NGROUP  = 118;              // ceil(480000 / 4096) output groups
static_assert(ITERS % 2 == 1, "pipeline tail assumes odd ITERS");

// padded bf16 audio: max read = 479232+240+3072+24+235872+6016+8 = 724464
constexpr int A_ELEMS = 724992;
// IR phase rows: row p holds ir_p[x] = ir[x-p], x in [-IR_PAD, ROW_IR-IR_PAD)
constexpr int IR_PAD  = 784;              // covers -8 - 256*3 = -776 front underrun
constexpr int ROW_IR  = 242752;           // >= 784+235872+6016+24+8 = 242704, mult of 16
constexpr int IR_ELEMS = 8 * ROW_IR;      // 1,942,016

// ws layout (bytes), all 16B aligned
constexpr size_t OFF_A   = 0;
constexpr size_t OFF_IR  = (size_t)A_ELEMS * 2;              // 1,449,984
constexpr size_t OFF_ACC = OFF_IR + (size_t)IR_ELEMS * 2;    // 5,334,016
constexpr size_t OFF_MAX = OFF_ACC + (size_t)N_AUDIO * 4;    // 7,254,016

__device__ __forceinline__ u16 f2bf(float f) {
    u32 u = __float_as_uint(f);
    u32 r = (u + 0x7fffu + ((u >> 16) & 1u)) >> 16;   // RTN
    return (u16)r;
}

// ---- kernel 1: convert inputs to bf16 (audio padded, IR in 8 phase rows), zero accum+slot
__global__ void prep_kernel(const float* __restrict__ audio, const float* __restrict__ ir,
                            u16* __restrict__ abuf, u16* __restrict__ irbuf,
                            float* __restrict__ accum, u32* __restrict__ slot) {
    int tid = blockIdx.x * blockDim.x + threadIdx.x;
    int nth = gridDim.x * blockDim.x;
    if (tid == 0) *slot = 0u;
    for (int i = tid; i < A_ELEMS; i += nth)
        abuf[i] = (i < N_AUDIO) ? f2bf(audio[i]) : (u16)0;
    for (int i = tid; i < IR_ELEMS; i += nth) {
        int p = i / ROW_IR;               // phase 0..7
        int x = (i - p * ROW_IR) - IR_PAD;
        int src = x - p;
        irbuf[i] = (src >= 0 && src < K_IR) ? f2bf(ir[src]) : (u16)0;
    }
    for (int i = tid; i < N_AUDIO; i += nth) accum[i] = 0.0f;
}

// ---- kernel 2: MFMA correlation, MT=4 x NT=4 tiles/wave (4096 outs), split-K via atomicAdd
// Manual 2-deep ping-pong pipeline: prefetch iter t+1 frags while issuing iter t MFMAs.
// __launch_bounds__(256,3) caps VGPRs ~170 so the compiler cannot spill-pipeline (R3 lesson).
__global__ __launch_bounds__(256, 3) void conv_kernel(const u16* __restrict__ abuf,
                                                      const u16* __restrict__ irbuf,
                                                      float* __restrict__ accum) {
    const int wave = threadIdx.x >> 6;
    const int lane = threadIdx.x & 63;
    const int gid  = blockIdx.x * 4 + wave;          // 0..4719
    const int s    = gid / NGROUP;                   // k-split 0..39
    const int g    = gid - s * NGROUP;               // output group 0..117

    const int m16 = lane & 15;                       // A row m / B col n / C col
    const int kq  = lane >> 4;                       // 0..3 (k-chunk quadrant)
    const int nh  = m16 >> 3;                        // n high bit
    const int ph  = m16 & 7;                         // IR phase row

    const int gbase = g * 4096;
    const int k0    = s * LSPLIT;

    const u16* aptr = abuf + gbase + 16 * m16 + 8 * kq + k0;
    const u16* bptr = irbuf + ph * ROW_IR + IR_PAD + k0 + 8 * (kq - nh);

    f32x4 acc[4][4];
    #pragma unroll
    for (int mt = 0; mt < 4; ++mt)
        #pragma unroll
        for (int nt = 0; nt < 4; ++nt)
            acc[mt][nt] = (f32x4){0.f, 0.f, 0.f, 0.f};

    auto loadA = [&](bf16x8 (&A)[4], int it) {
        const u16* p = aptr + 32 * it;
        #pragma unroll
        for (int mt = 0; mt < 4; ++mt) A[mt] = *(const bf16x8*)(p + 1024 * mt);
    };
    auto loadB = [&](bf16x8 (&B)[4], int it) {
        const u16* p = bptr + 32 * it;
        #pragma unroll
        for (int nt = 0; nt < 4; ++nt) B[nt] = *(const bf16x8*)(p - 256 * nt);
    };
    auto domfma = [&](bf16x8 (&A)[4], bf16x8 (&B)[4]) {
        #pragma unroll
        for (int mt = 0; mt < 4; ++mt)
            #pragma unroll
            for (int nt = 0; nt < 4; ++nt)
                acc[mt][nt] = __builtin_amdgcn_mfma_f32_16x16x32_bf16(A[mt], B[nt], acc[mt][nt], 0, 0, 0);
    };

    bf16x8 aP[4], bP[4], aQ[4], bQ[4];
    loadA(aP, 0); loadB(bP, 0);
    for (int it = 0; it + 2 < ITERS; it += 2) {
        loadA(aQ, it + 1); loadB(bQ, it + 1);
        domfma(aP, bP);
        loadA(aP, it + 2); loadB(bP, it + 2);
        domfma(aQ, bQ);
    }
    domfma(aP, bP);   // final (odd) iteration, frags already resident

    // C/D layout: col = lane&15, row = (lane>>4)*4 + r  ->  t = base + 16*row + col
    #pragma unroll
    for (int mt = 0; mt < 4; ++mt) {
        #pragma unroll
        for (int nt = 0; nt < 4; ++nt) {
            int base = gbase + 1024 * mt + 256 * nt + 64 * kq + m16;
            #pragma unroll
            for (int r = 0; r < 4; ++r) {
                int t = base + 16 * r;
                if (t < N_AUDIO) atomicAdd(&accum[t], acc[mt][nt][r]);
            }
        }
    }
}

// ---- kernel 3: global abs-max (float-bits atomicMax works for non-negative floats)
__global__ __launch_bounds__(256) void reduce_max_kernel(const float* __restrict__ accum,
                                                         u32* __restrict__ slot) {
    int tid = blockIdx.x * blockDim.x + threadIdx.x;
    int nth = gridDim.x * blockDim.x;
    float m = 0.f;
    for (int i = tid; i < N_AUDIO; i += nth) m = fmaxf(m, fabsf(accum[i]));
    for (int off = 32; off > 0; off >>= 1) m = fmaxf(m, __shfl_down(m, off, 64));
    __shared__ float smax[4];
    if ((threadIdx.x & 63) == 0) smax[threadIdx.x >> 6] = m;
    __syncthreads();
    if (threadIdx.x == 0) {
        float b = fmaxf(fmaxf(smax[0], smax[1]), fmaxf(smax[2], smax[3]));
        atomicMax(slot, __float_as_uint(b));
    }
}

// ---- kernel 4: normalize
__global__ __launch_bounds__(256) void scale_kernel(const float* __restrict__ accum,
                                                    const u32* __restrict__ slot,
                                                    float* __restrict__ out) {
    float inv = 1.0f / __uint_as_float(*slot);
    int t = blockIdx.x * 256 + threadIdx.x;
    if (t < N_AUDIO) out[t] = accum[t] * inv;
}

extern "C" void kernel_launch(void* const* d_in, const int* in_sizes, int n_in,
                              void* d_out, int out_size, void* d_ws, size_t ws_size,
                              hipStream_t stream) {
    const float* audio = (const float*)d_in[0];
    const float* ir    = (const float*)d_in[1];
    float* out = (float*)d_out;

    char* ws = (char*)d_ws;
    u16*   abuf  = (u16*)(ws + OFF_A);
    u16*   irbuf = (u16*)(ws + OFF_IR);
    float* accum = (float*)(ws + OFF_ACC);
    u32*   slot  = (u32*)(ws + OFF_MAX);

    prep_kernel<<<2048, 256, 0, stream>>>(audio, ir, abuf, irbuf, accum, slot);
    conv_kernel<<<NGROUP * NSPLIT / 4, 256, 0, stream>>>(abuf, irbuf, accum);
    reduce_max_kernel<<<960, 256, 0, stream>>>(accum, slot);
    scale_kernel<<<(N_AUDIO + 255) / 256, 256, 0, stream>>>(accum, slot, out);
}

// Round 5
// 268.656 us; speedup vs baseline: 2.6665x; 2.4038x over previous
//
#include <hip/hip_runtime.h>
#include <hip/hip_bf16.h>

typedef unsigned short u16;
typedef unsigned int   u32;

typedef __attribute__((ext_vector_type(8))) short bf16x8;  // 8 bf16 = 4 VGPRs
typedef __attribute__((ext_vector_type(4))) float f32x4;   // MFMA 16x16 accum

constexpr int N_AUDIO = 480000;
constexpr int K_IR    = 240000;

// Block tile: 16384 outputs (4 waves x MT4 x NT4 x 256). K split across blocks.
constexpr int NSPLIT  = 24;
constexpr int LSPLIT  = 10240;            // 24*10240 = 245760 >= 240783 (K+15+768)
constexpr int BK      = 512;              // taps per LDS chunk
constexpr int NCHUNK  = LSPLIT / BK;      // 20
constexpr int NGROUP  = 30;               // ceil(480000/16384)

// LDS window per chunk: elems [k0c-776, k0c+552) per phase row = 1328 elems
constexpr int WIN_CH  = 166;              // 1328/8  16B-chunks along k
constexpr int NITEM   = WIN_CH * 8;       // 1328 16B items (phase-interleaved)

// padded bf16 audio
constexpr int A_ELEMS = 737280;           // covers 491520 outputs + 245760 K-span
// IR phase rows: row p holds ir_p[x] = ir[x-p], x in [-IR_PAD, ROW_IR-IR_PAD)
constexpr int IR_PAD  = 784;
constexpr int ROW_IR  = 246784;           // >= 784 + 245760 + 552, mult of 16
constexpr int IR_ELEMS = 8 * ROW_IR;      // 1,974,272

// ws layout (bytes), all 16B aligned
constexpr size_t OFF_A   = 0;
constexpr size_t OFF_IR  = (size_t)A_ELEMS * 2;              // 1,474,560
constexpr size_t OFF_ACC = OFF_IR + (size_t)IR_ELEMS * 2;    // 5,423,104
constexpr size_t OFF_MAX = OFF_ACC + (size_t)N_AUDIO * 4;    // 7,343,104

__device__ __forceinline__ u16 f2bf(float f) {
    u32 u = __float_as_uint(f);
    u32 r = (u + 0x7fffu + ((u >> 16) & 1u)) >> 16;   // RTN
    return (u16)r;
}

// ---- kernel 1: convert inputs to bf16 (audio padded, IR in 8 phase rows), zero accum+slot
__global__ void prep_kernel(const float* __restrict__ audio, const float* __restrict__ ir,
                            u16* __restrict__ abuf, u16* __restrict__ irbuf,
                            float* __restrict__ accum, u32* __restrict__ slot) {
    int tid = blockIdx.x * blockDim.x + threadIdx.x;
    int nth = gridDim.x * blockDim.x;
    if (tid == 0) *slot = 0u;
    for (int i = tid; i < A_ELEMS; i += nth)
        abuf[i] = (i < N_AUDIO) ? f2bf(audio[i]) : (u16)0;
    for (int i = tid; i < IR_ELEMS; i += nth) {
        int p = i / ROW_IR;               // phase 0..7
        int x = (i - p * ROW_IR) - IR_PAD;
        int src = x - p;
        irbuf[i] = (src >= 0 && src < K_IR) ? f2bf(ir[src]) : (u16)0;
    }
    for (int i = tid; i < N_AUDIO; i += nth) accum[i] = 0.0f;
}

// ---- kernel 2: MFMA correlation. Block = 4 waves, same (s,g), 16384 outputs.
// B (IR, 8 phase rows) double-buffered in LDS per 512-tap chunk; A from global.
// Per wave: MT=4 x NT=4 (4096 outputs). Split-K via atomicAdd epilogue.
__global__ __launch_bounds__(256) void conv_kernel(const u16* __restrict__ abuf,
                                                   const u16* __restrict__ irbuf,
                                                   float* __restrict__ accum) {
    // phase-interleaved: item idx = kchunk*8 + phase, 16B each -> bank-uniform b128
    __shared__ u16 lbuf[2][NITEM * 8];    // 2 x 21,248 B

    const int tid  = threadIdx.x;
    const int wave = tid >> 6;
    const int lane = tid & 63;
    const int bid  = blockIdx.x;
    const int s    = bid / NGROUP;                   // k-split 0..23
    const int g    = bid - s * NGROUP;               // output group 0..29

    const int m16 = lane & 15;                       // A row m / B col n / C col
    const int kq  = lane >> 4;                       // 0..3 (k-chunk quadrant)
    const int nh  = m16 >> 3;                        // n high bit
    const int ph  = m16 & 7;                         // IR phase row

    const int k0 = s * LSPLIT;

    // A base: audio[g*16384 + wave*4096 + 16*m + 8*kq + k]
    const u16* aptr0 = abuf + g * 16384 + wave * 4096 + 16 * m16 + 8 * kq + k0;
    // staging source: item idx -> phase p=idx&7, kchunk cc=idx>>3
    // global elem = p*ROW_IR + (IR_PAD-776) + k0 + chunk*BK + 8*cc   (16B aligned)
    const u16* irb = irbuf + (IR_PAD - 776) + k0;

    f32x4 acc[4][4];
    #pragma unroll
    for (int mt = 0; mt < 4; ++mt)
        #pragma unroll
        for (int nt = 0; nt < 4; ++nt)
            acc[mt][nt] = (f32x4){0.f, 0.f, 0.f, 0.f};

    // prologue: stage chunk 0 into buffer 0
    #pragma unroll
    for (int r = 0; r < 6; ++r) {
        int idx = tid + 256 * r;
        if (idx < NITEM) {
            int p = idx & 7, cc = idx >> 3;
            bf16x8 v = *(const bf16x8*)(irb + (size_t)p * ROW_IR + 8 * cc);
            *(bf16x8*)&lbuf[0][idx * 8] = v;
        }
    }
    __syncthreads();

    for (int c = 0; c < NCHUNK; ++c) {
        const int cur = c & 1;
        // issue staging loads for chunk c+1 (latency hides under compute)
        bf16x8 st[6];
        const bool has = (c + 1 < NCHUNK);
        if (has) {
            #pragma unroll
            for (int r = 0; r < 6; ++r) {
                int idx = tid + 256 * r;
                if (idx < NITEM) {
                    int p = idx & 7, cc = idx >> 3;
                    st[r] = *(const bf16x8*)(irb + (size_t)p * ROW_IR + (c + 1) * BK + 8 * cc);
                }
            }
        }

        // compute: 16 k-steps of 32 taps from lbuf[cur]
        const u16* ap = aptr0 + c * BK;
        #pragma unroll 2
        for (int it2 = 0; it2 < BK / 32; ++it2) {
            bf16x8 b[4], a[4];
            #pragma unroll
            for (int nt = 0; nt < 4; ++nt) {
                // e0/8 = 97 + 4*it2 + (kq-nh) - 32*nt ; u16 index = chunk*64 + ph*8
                int ch = 97 + 4 * it2 + (kq - nh) - 32 * nt;
                b[nt] = *(const bf16x8*)&lbuf[cur][ch * 64 + ph * 8];
            }
            #pragma unroll
            for (int mt = 0; mt < 4; ++mt)
                a[mt] = *(const bf16x8*)(ap + 1024 * mt + 32 * it2);
            #pragma unroll
            for (int mt = 0; mt < 4; ++mt)
                #pragma unroll
                for (int nt = 0; nt < 4; ++nt)
                    acc[mt][nt] = __builtin_amdgcn_mfma_f32_16x16x32_bf16(a[mt], b[nt], acc[mt][nt], 0, 0, 0);
        }

        // commit staged data to the other buffer, then barrier
        if (has) {
            #pragma unroll
            for (int r = 0; r < 6; ++r) {
                int idx = tid + 256 * r;
                if (idx < NITEM) *(bf16x8*)&lbuf[cur ^ 1][idx * 8] = st[r];
            }
        }
        __syncthreads();
    }

    // epilogue: C/D layout col = lane&15, row = kq*4 + r -> t = base + 16*row + col
    const int gbase_w = g * 16384 + wave * 4096;
    #pragma unroll
    for (int mt = 0; mt < 4; ++mt) {
        #pragma unroll
        for (int nt = 0; nt < 4; ++nt) {
            int base = gbase_w + 1024 * mt + 256 * nt + 64 * kq + m16;
            #pragma unroll
            for (int r = 0; r < 4; ++r) {
                int t = base + 16 * r;
                if (t < N_AUDIO) atomicAdd(&accum[t], acc[mt][nt][r]);
            }
        }
    }
}

// ---- kernel 3: global abs-max (float-bits atomicMax works for non-negative floats)
__global__ __launch_bounds__(256) void reduce_max_kernel(const float* __restrict__ accum,
                                                         u32* __restrict__ slot) {
    int tid = blockIdx.x * blockDim.x + threadIdx.x;
    int nth = gridDim.x * blockDim.x;
    float m = 0.f;
    for (int i = tid; i < N_AUDIO; i += nth) m = fmaxf(m, fabsf(accum[i]));
    for (int off = 32; off > 0; off >>= 1) m = fmaxf(m, __shfl_down(m, off, 64));
    __shared__ float smax[4];
    if ((threadIdx.x & 63) == 0) smax[threadIdx.x >> 6] = m;
    __syncthreads();
    if (threadIdx.x == 0) {
        float b = fmaxf(fmaxf(smax[0], smax[1]), fmaxf(smax[2], smax[3]));
        atomicMax(slot, __float_as_uint(b));
    }
}

// ---- kernel 4: normalize
__global__ __launch_bounds__(256) void scale_kernel(const float* __restrict__ accum,
                                                    const u32* __restrict__ slot,
                                                    float* __restrict__ out) {
    float inv = 1.0f / __uint_as_float(*slot);
    int t = blockIdx.x * 256 + threadIdx.x;
    if (t < N_AUDIO) out[t] = accum[t] * inv;
}

extern "C" void kernel_launch(void* const* d_in, const int* in_sizes, int n_in,
                              void* d_out, int out_size, void* d_ws, size_t ws_size,
                              hipStream_t stream) {
    const float* audio = (const float*)d_in[0];
    const float* ir    = (const float*)d_in[1];
    float* out = (float*)d_out;

    char* ws = (char*)d_ws;
    u16*   abuf  = (u16*)(ws + OFF_A);
    u16*   irbuf = (u16*)(ws + OFF_IR);
    float* accum = (float*)(ws + OFF_ACC);
    u32*   slot  = (u32*)(ws + OFF_MAX);

    prep_kernel<<<2048, 256, 0, stream>>>(audio, ir, abuf, irbuf, accum, slot);
    conv_kernel<<<NGROUP * NSPLIT, 256, 0, stream>>>(abuf, irbuf, accum);
    reduce_max_kernel<<<960, 256, 0, stream>>>(accum, slot);
    scale_kernel<<<(N_AUDIO + 255) / 256, 256, 0, stream>>>(accum, slot, out);
}